// Round 6
// baseline (72.710 us; speedup 1.0000x reference)
//
#include <hip/hip_runtime.h>

#define NHEAD 256

typedef _Float16 f16x8 __attribute__((ext_vector_type(8)));
typedef float f32x4 __attribute__((ext_vector_type(4)));

// ---- swizzled [64][64] f16 matrix helpers (16B-unit XOR swizzle: unit ^= row&7)
__device__ __forceinline__ int mel(int r, int c) {
  return (r << 6) + ((((c >> 3) ^ r) & 7) << 3) + (c & 7);
}
__device__ __forceinline__ f16x8 ldfrag(const _Float16* M, int r, int u) {
  return *(const f16x8*)(M + (r << 6) + (((u ^ r) & 7) << 3));
}
__device__ __forceinline__ f32x4 MF(f16x8 a, f16x8 b, f32x4 c) {
  return __builtin_amdgcn_mfma_f32_16x16x32_f16(a, b, c, 0, 0, 0);
}

// prep matmul, 8 waves: D(rows dr0+r, r<limit) = A(rows r) * B, BT = B^T given.
// wave w: colblock w&3, rowblocks ib = (w>>2), (w>>2)+2,...
// Row-masked: D row r depends only on A row r (MFMA rows independent), so
// junk/racing source rows r >= limit only feed masked-out outputs.
__device__ __forceinline__ void mmstep8(const _Float16* A, const _Float16* BT,
                                        _Float16* Dr, _Float16* Dt, int dr0,
                                        int nrb, int limit, int w, int c15,
                                        int g) {
  const int wc = w & 3;
  f16x8 b0 = ldfrag(BT, (wc << 4) + c15, g);
  f16x8 b1 = ldfrag(BT, (wc << 4) + c15, 4 + g);
  for (int ib = (w >> 2); ib < nrb; ib += 2) {
    f32x4 acc = {0.f, 0.f, 0.f, 0.f};
    f16x8 a0 = ldfrag(A, (ib << 4) + c15, g);
    f16x8 a1 = ldfrag(A, (ib << 4) + c15, 4 + g);
    acc = MF(a0, b0, acc);
    acc = MF(a1, b1, acc);
#pragma unroll
    for (int j = 0; j < 4; ++j) {
      const int lr = (ib << 4) + (g << 2) + j;
      if (lr < limit) {
        const int rr = dr0 + lr;
        const int cc = (wc << 4) + c15;
        const _Float16 v = (_Float16)acc[j];
        Dr[mel(rr, cc)] = v;
        Dt[mel(cc, rr)] = v;
      }
    }
  }
}

// ---------------- fused: solve + prep + lag-256 chunked scan ----------------
// x_l = sum_{t<4} sum_{d<64} u[l-64t-d]*(G^t K[d]) + G^4 x_{l-256},  G = Ab^64
// 8 waves: chain = w&3, half = w>>2 owns 32 output rows. Main loop barrier-free.
__global__ __launch_bounds__(512, 2) void hippo_fused(
    const float* __restrict__ u, const float* __restrict__ Ag,
    const float* __restrict__ Bv, const float* __restrict__ dtv,
    float* __restrict__ out) {
  const int h = blockIdx.x;
  const int t = threadIdx.x;
  const int w = t >> 6;
  const int lane = t & 63;
  const int c15 = lane & 15;
  const int g = lane >> 4;

  __shared__ __align__(16) _Float16 URV[4 * 4616];   // 4 shift-staggered reversed u
  __shared__ __align__(16) _Float16 RING[4 * 4096];  // per-chain X state (f16)
  // UNI: phase1 f32 solve {M | X[64][68] | invd}; phase2 f16 PB0|PB1|PB4|PB5
  __shared__ __align__(16) char UNI[49152];
  __shared__ __align__(16) _Float16 PB23[2 * 4096];  // PB2|PB3
  __shared__ float RED[8][64];
  __shared__ float KC[64];

  float* Ms = (float*)UNI;                       // [64][64]
  float* Xs = (float*)(UNI + 16384);             // [64][68]
  float* invd = (float*)(UNI + 16384 + 17408);
  _Float16* PB0 = (_Float16*)UNI;
  _Float16* PB1 = PB0 + 4096;
  _Float16* PB4 = (_Float16*)(UNI + 16384);
  _Float16* PB5 = PB4 + 4096;
  _Float16* PB2 = PB23;
  _Float16* PB3 = PB23 + 4096;

  // --- stage URV + init solve ---
  for (int s = 0; s < 4; ++s)
    for (int x = t; x < 4616; x += 512) {
      const int q = 4095 - x - s;
      URV[s * 4616 + x] = (q >= 0) ? (_Float16)u[q] : (_Float16)0.f;
    }
  const float dt = dtv[h];
  const float* Ah = Ag + (size_t)h * 4096;
  for (int idx = t; idx < 4096; idx += 512) {
    const int r = idx >> 6, c = idx & 63;
    const float a = Ah[idx];
    const float half_ = 0.5f * dt * a;
    const float id = (r == c) ? 1.0f : 0.0f;
    Ms[r * 64 + c] = id - half_;
    Xs[r * 68 + c] = id + half_;
  }
  if (t < 64) {
    Xs[t * 68 + 64] = dt * Bv[h * 64 + t];
    Xs[t * 68 + 65] = 0.f;
    Xs[t * 68 + 66] = 0.f;
    Xs[t * 68 + 67] = 0.f;
    invd[t] = 1.0f / (1.0f - 0.5f * dt * Ah[t * 65]);
  }
  __syncthreads();

  // --- 4-pivot blocked forward substitution: X <- M^{-1} X ---
  for (int k = 0; k < 64; k += 4) {
    if (t < 68) {
      const int c = t;
      const float x0 = Xs[k * 68 + c] * invd[k];
      const float x1 = (Xs[(k + 1) * 68 + c] - Ms[(k + 1) * 64 + k] * x0) * invd[k + 1];
      const float x2 = (Xs[(k + 2) * 68 + c] - Ms[(k + 2) * 64 + k] * x0 -
                        Ms[(k + 2) * 64 + k + 1] * x1) * invd[k + 2];
      const float x3 = (Xs[(k + 3) * 68 + c] - Ms[(k + 3) * 64 + k] * x0 -
                        Ms[(k + 3) * 64 + k + 1] * x1 -
                        Ms[(k + 3) * 64 + k + 2] * x2) * invd[k + 3];
      Xs[k * 68 + c] = x0;
      Xs[(k + 1) * 68 + c] = x1;
      Xs[(k + 2) * 68 + c] = x2;
      Xs[(k + 3) * 68 + c] = x3;
    }
    __syncthreads();
    const int nwork = (60 - k) * 17;
    for (int idx = t; idx < nwork; idx += 512) {
      const int r = k + 4 + idx / 17;
      const int cu = (idx % 17) * 4;
      float4 xr = *(float4*)&Xs[r * 68 + cu];
      const float m0 = Ms[r * 64 + k], m1 = Ms[r * 64 + k + 1];
      const float m2 = Ms[r * 64 + k + 2], m3 = Ms[r * 64 + k + 3];
      const float4 a0 = *(float4*)&Xs[k * 68 + cu];
      const float4 a1 = *(float4*)&Xs[(k + 1) * 68 + cu];
      const float4 a2 = *(float4*)&Xs[(k + 2) * 68 + cu];
      const float4 a3 = *(float4*)&Xs[(k + 3) * 68 + cu];
      xr.x -= m0 * a0.x + m1 * a1.x + m2 * a2.x + m3 * a3.x;
      xr.y -= m0 * a0.y + m1 * a1.y + m2 * a2.y + m3 * a3.y;
      xr.z -= m0 * a0.z + m1 * a1.z + m2 * a2.z + m3 * a3.z;
      xr.w -= m0 * a0.w + m1 * a1.w + m2 * a2.w + m3 * a3.w;
      *(float4*)&Xs[r * 68 + cu] = xr;
    }
    __syncthreads();
  }

  // --- Ab f16 (row+trans, overwrites dead M); Kmat row 0 = Bb ---
  for (int idx = t; idx < 4096; idx += 512) {
    const int r = idx >> 6, cc = idx & 63;
    const _Float16 v = (_Float16)Xs[r * 68 + cc];
    PB0[mel(r, cc)] = v;
    PB1[mel(cc, r)] = v;
  }
  if (t < 64) {
    const float bb = Xs[t * 68 + 64];
    KC[t] = bb;
    PB2[mel(0, t)] = (_Float16)bb;
    PB3[mel(t, 0)] = (_Float16)bb;
  }
  __syncthreads();

  // --- Kmat row 1 = Ab@K0, one f32 matvec round (Xs still live) ---
  {
    const int mrow = t & 63;
    const float4* ar = (const float4*)(Xs + mrow * 68 + w * 8);
    const float4 av0 = ar[0], av1 = ar[1];
    const int jb = w * 8;
    RED[w][mrow] = av0.x * KC[jb] + av0.y * KC[jb + 1] + av0.z * KC[jb + 2] +
                   av0.w * KC[jb + 3] + av1.x * KC[jb + 4] + av1.y * KC[jb + 5] +
                   av1.z * KC[jb + 6] + av1.w * KC[jb + 7];
    __syncthreads();
    if (t < 64) {
      float s2 = 0.f;
#pragma unroll
      for (int qq = 0; qq < 8; ++qq) s2 += RED[qq][t];
      PB2[mel(1, t)] = (_Float16)s2;
      PB3[mel(t, 1)] = (_Float16)s2;
    }
    __syncthreads();
  }

  // --- power ladder + log-doubling Kmat (PB4/PB5 overwrite dead Xs) ---
  mmstep8(PB0, PB1, PB4, PB5, 0, 4, 64, w, c15, g); __syncthreads();  // Ab^2
  mmstep8(PB2, PB4, PB2, PB3, 2, 1, 2, w, c15, g);  __syncthreads();  // K[2,3]
  mmstep8(PB4, PB5, PB0, PB1, 0, 4, 64, w, c15, g); __syncthreads();  // Ab^4
  mmstep8(PB2, PB0, PB2, PB3, 4, 1, 4, w, c15, g);  __syncthreads();  // K[4..7]
  mmstep8(PB0, PB1, PB4, PB5, 0, 4, 64, w, c15, g); __syncthreads();  // Ab^8
  mmstep8(PB2, PB4, PB2, PB3, 8, 1, 8, w, c15, g);  __syncthreads();  // K[8..15]
  mmstep8(PB4, PB5, PB0, PB1, 0, 4, 64, w, c15, g); __syncthreads();  // Ab^16
  mmstep8(PB2, PB0, PB2, PB3, 16, 1, 16, w, c15, g); __syncthreads(); // K[16..31]
  mmstep8(PB0, PB1, PB4, PB5, 0, 4, 64, w, c15, g); __syncthreads();  // Ab^32
  mmstep8(PB2, PB4, PB2, PB3, 32, 2, 32, w, c15, g); __syncthreads(); // K[32..63]
  mmstep8(PB4, PB5, PB0, PB1, 0, 4, 64, w, c15, g); __syncthreads();  // G=Ab^64 ->PB0, G^T->PB1

  f16x8 bt[8][4];  // conv B-frags: [2*t + khalf][colblock]
  f16x8 bc[2][4];  // correction B-frags (G^4)^T
  auto LB = [&](f16x8* dst, const _Float16* BT, int kk) {
#pragma unroll
    for (int nb = 0; nb < 4; ++nb)
      dst[nb] = ldfrag(BT, (nb << 4) + c15, (kk << 2) + g);
  };

  LB(bt[0], PB3, 0); LB(bt[1], PB3, 1);                               // BK0 = Kmat
  mmstep8(PB2, PB0, PB4, PB5, 0, 4, 64, w, c15, g); __syncthreads();  // BK1 = Kmat@G^T
  LB(bt[2], PB5, 0); LB(bt[3], PB5, 1);
  mmstep8(PB4, PB0, PB2, PB3, 0, 4, 64, w, c15, g); __syncthreads();  // BK2
  LB(bt[4], PB3, 0); LB(bt[5], PB3, 1);
  mmstep8(PB2, PB0, PB4, PB5, 0, 4, 64, w, c15, g); __syncthreads();  // BK3
  LB(bt[6], PB5, 0); LB(bt[7], PB5, 1);
  mmstep8(PB1, PB0, PB2, PB3, 0, 4, 64, w, c15, g); __syncthreads();  // (G^2)^T, G^2
  mmstep8(PB2, PB3, PB4, PB1, 0, 4, 64, w, c15, g); __syncthreads();  // (G^4)^T; G^4->PB1
  LB(bc[0], PB1, 0); LB(bc[1], PB1, 1);
  __syncthreads();

  // --- main loop: 16 stages/chain, 2 waves/chain, barrier-free ---
  const int chain = w & 3;
  const int half = w >> 2;
  _Float16* ringw = RING + (chain << 12);
  float* outh = out + (h << 6);
  const int lanebase = (g << 3) - c15;

#pragma unroll 1
  for (int mstep = 0; mstep < 16; ++mstep) {
    const int c = chain + (mstep << 2);
    f32x4 acc[2][4];
#pragma unroll
    for (int ibl = 0; ibl < 2; ++ibl)
#pragma unroll
      for (int nb = 0; nb < 4; ++nb) acc[ibl][nb] = f32x4{0.f, 0.f, 0.f, 0.f};

    // conv over 4 lag-tiles (K-dim 256), Toeplitz A from shifted reversed-u
#pragma unroll
    for (int ks = 0; ks < 8; ++ks) {
      const int tt = ks >> 1;
      const int base = 4095 - 64 * (c - tt) + ((ks & 1) << 5) + lanebase;
#pragma unroll
      for (int ibl = 0; ibl < 2; ++ibl) {
        const int ib = (half << 1) + ibl;
        const int m0 = base - (ib << 4);
        const int lo = m0 & 3;
        const uint2* p = (const uint2*)(URV + lo * 4616 + (m0 - lo));
        union { f16x8 hv; uint2 u2[2]; } ua;
        ua.u2[0] = p[0];
        ua.u2[1] = p[1];
#pragma unroll
        for (int nb = 0; nb < 4; ++nb)
          acc[ibl][nb] = MF(ua.hv, bt[ks][nb], acc[ibl][nb]);
      }
    }
    // correction: X_{c-4} @ (G^4)^T  (ring rows are this wave's own)
    if (mstep > 0) {
#pragma unroll
      for (int kk = 0; kk < 2; ++kk)
#pragma unroll
        for (int ibl = 0; ibl < 2; ++ibl) {
          const int row = (((half << 1) + ibl) << 4) + c15;
          const f16x8 a = ldfrag(ringw, row, (kk << 2) + g);
#pragma unroll
          for (int nb = 0; nb < 4; ++nb)
            acc[ibl][nb] = MF(a, bc[kk][nb], acc[ibl][nb]);
        }
    }
    // write state ring (f16) + global out (f32), both wave-private
    const int ob = c << 6;
#pragma unroll
    for (int ibl = 0; ibl < 2; ++ibl)
#pragma unroll
      for (int nb = 0; nb < 4; ++nb) {
        const int n = (nb << 4) + c15;
#pragma unroll
        for (int j = 0; j < 4; ++j) {
          const int i = (((half << 1) + ibl) << 4) + (g << 2) + j;
          const float v = acc[ibl][nb][j];
          ringw[mel(i, n)] = (_Float16)v;
          outh[(size_t)(ob + i) * 16384 + n] = v;
        }
      }
  }
}

extern "C" void kernel_launch(void* const* d_in, const int* in_sizes, int n_in,
                              void* d_out, int out_size, void* d_ws,
                              size_t ws_size, hipStream_t stream) {
  const float* u = (const float*)d_in[0];
  const float* A = (const float*)d_in[1];
  const float* B = (const float*)d_in[2];
  const float* dt = (const float*)d_in[3];
  float* out = (float*)d_out;
  hippo_fused<<<dim3(NHEAD), dim3(512), 0, stream>>>(u, A, B, dt, out);
}

// Round 7
// 71.530 us; speedup vs baseline: 1.0165x; 1.0165x over previous
//
#include <hip/hip_runtime.h>

#define NHEAD 256

typedef _Float16 f16x8 __attribute__((ext_vector_type(8)));
typedef float f32x4 __attribute__((ext_vector_type(4)));

// ---- swizzled [64][64] f16 matrix helpers (16B-unit XOR swizzle: unit ^= row&7)
__device__ __forceinline__ int mel(int r, int c) {
  return (r << 6) + ((((c >> 3) ^ r) & 7) << 3) + (c & 7);
}
__device__ __forceinline__ f16x8 ldfrag(const _Float16* M, int r, int u) {
  return *(const f16x8*)(M + (r << 6) + (((u ^ r) & 7) << 3));
}
__device__ __forceinline__ f32x4 MF(f16x8 a, f16x8 b, f32x4 c) {
  return __builtin_amdgcn_mfma_f32_16x16x32_f16(a, b, c, 0, 0, 0);
}

// prep matmul, 8 waves: D(rows dr0+r, r<limit) = A(rows r) * B, BT = B^T given.
// wave w: colblock w&3, rowblocks ib = (w>>2), (w>>2)+2,...
// Row-masked: D row r depends only on A row r (MFMA rows independent), so
// junk/racing source rows r >= limit only feed masked-out outputs.
__device__ __forceinline__ void mmstep8(const _Float16* A, const _Float16* BT,
                                        _Float16* Dr, _Float16* Dt, int dr0,
                                        int nrb, int limit, int w, int c15,
                                        int g) {
  const int wc = w & 3;
  f16x8 b0 = ldfrag(BT, (wc << 4) + c15, g);
  f16x8 b1 = ldfrag(BT, (wc << 4) + c15, 4 + g);
  for (int ib = (w >> 2); ib < nrb; ib += 2) {
    f32x4 acc = {0.f, 0.f, 0.f, 0.f};
    f16x8 a0 = ldfrag(A, (ib << 4) + c15, g);
    f16x8 a1 = ldfrag(A, (ib << 4) + c15, 4 + g);
    acc = MF(a0, b0, acc);
    acc = MF(a1, b1, acc);
#pragma unroll
    for (int j = 0; j < 4; ++j) {
      const int lr = (ib << 4) + (g << 2) + j;
      if (lr < limit) {
        const int rr = dr0 + lr;
        const int cc = (wc << 4) + c15;
        const _Float16 v = (_Float16)acc[j];
        Dr[mel(rr, cc)] = v;
        Dt[mel(cc, rr)] = v;
      }
    }
  }
}

// ---------------- fused: solve + prep + lag-256 chunked scan ----------------
// x_l = sum_{t<4} sum_{d<64} u[l-64t-d]*(G^t K[d]) + G^4 x_{l-256},  G = Ab^64
// 8 waves: chain = w&3, half = w>>2 owns 32 output rows. Main loop barrier-free.
__global__ __launch_bounds__(512, 2) void hippo_fused(
    const float* __restrict__ u, const float* __restrict__ Ag,
    const float* __restrict__ Bv, const float* __restrict__ dtv,
    float* __restrict__ out) {
  const int h = blockIdx.x;
  const int t = threadIdx.x;
  const int w = t >> 6;
  const int lane = t & 63;
  const int c15 = lane & 15;
  const int g = lane >> 4;

  __shared__ __align__(16) _Float16 URV[4 * 4616];   // 4 shift-staggered reversed u
  __shared__ __align__(16) _Float16 RING[4 * 4096];  // per-chain X state (f16)
  // UNI: phase1 f32 solve {M | X[64][68] | invd}; phase2 f16 PB0|PB1|PB4|PB5
  __shared__ __align__(16) char UNI[49152];
  __shared__ __align__(16) _Float16 PB23[2 * 4096];  // PB2|PB3
  __shared__ float RED[8][64];
  __shared__ float KC[64];

  float* Ms = (float*)UNI;                       // [64][64]
  float* Xs = (float*)(UNI + 16384);             // [64][68]
  float* invd = (float*)(UNI + 16384 + 17408);
  _Float16* PB0 = (_Float16*)UNI;
  _Float16* PB1 = PB0 + 4096;
  _Float16* PB4 = (_Float16*)(UNI + 16384);
  _Float16* PB5 = PB4 + 4096;
  _Float16* PB2 = PB23;
  _Float16* PB3 = PB23 + 4096;

  // --- stage URV + init solve ---
  for (int s = 0; s < 4; ++s)
    for (int x = t; x < 4616; x += 512) {
      const int q = 4095 - x - s;
      URV[s * 4616 + x] = (q >= 0) ? (_Float16)u[q] : (_Float16)0.f;
    }
  const float dt = dtv[h];
  const float* Ah = Ag + (size_t)h * 4096;
  for (int idx = t; idx < 4096; idx += 512) {
    const int r = idx >> 6, c = idx & 63;
    const float a = Ah[idx];
    const float half_ = 0.5f * dt * a;
    const float id = (r == c) ? 1.0f : 0.0f;
    Ms[r * 64 + c] = id - half_;
    Xs[r * 68 + c] = id + half_;
  }
  if (t < 64) {
    Xs[t * 68 + 64] = dt * Bv[h * 64 + t];
    Xs[t * 68 + 65] = 0.f;
    Xs[t * 68 + 66] = 0.f;
    Xs[t * 68 + 67] = 0.f;
    invd[t] = 1.0f / (1.0f - 0.5f * dt * Ah[t * 65]);
  }
  __syncthreads();

  // --- 4-pivot blocked forward substitution: X <- M^{-1} X ---
  for (int k = 0; k < 64; k += 4) {
    if (t < 68) {
      const int c = t;
      const float x0 = Xs[k * 68 + c] * invd[k];
      const float x1 = (Xs[(k + 1) * 68 + c] - Ms[(k + 1) * 64 + k] * x0) * invd[k + 1];
      const float x2 = (Xs[(k + 2) * 68 + c] - Ms[(k + 2) * 64 + k] * x0 -
                        Ms[(k + 2) * 64 + k + 1] * x1) * invd[k + 2];
      const float x3 = (Xs[(k + 3) * 68 + c] - Ms[(k + 3) * 64 + k] * x0 -
                        Ms[(k + 3) * 64 + k + 1] * x1 -
                        Ms[(k + 3) * 64 + k + 2] * x2) * invd[k + 3];
      Xs[k * 68 + c] = x0;
      Xs[(k + 1) * 68 + c] = x1;
      Xs[(k + 2) * 68 + c] = x2;
      Xs[(k + 3) * 68 + c] = x3;
    }
    __syncthreads();
    const int nwork = (60 - k) * 17;
    for (int idx = t; idx < nwork; idx += 512) {
      const int r = k + 4 + idx / 17;
      const int cu = (idx % 17) * 4;
      float4 xr = *(float4*)&Xs[r * 68 + cu];
      const float m0 = Ms[r * 64 + k], m1 = Ms[r * 64 + k + 1];
      const float m2 = Ms[r * 64 + k + 2], m3 = Ms[r * 64 + k + 3];
      const float4 a0 = *(float4*)&Xs[k * 68 + cu];
      const float4 a1 = *(float4*)&Xs[(k + 1) * 68 + cu];
      const float4 a2 = *(float4*)&Xs[(k + 2) * 68 + cu];
      const float4 a3 = *(float4*)&Xs[(k + 3) * 68 + cu];
      xr.x -= m0 * a0.x + m1 * a1.x + m2 * a2.x + m3 * a3.x;
      xr.y -= m0 * a0.y + m1 * a1.y + m2 * a2.y + m3 * a3.y;
      xr.z -= m0 * a0.z + m1 * a1.z + m2 * a2.z + m3 * a3.z;
      xr.w -= m0 * a0.w + m1 * a1.w + m2 * a2.w + m3 * a3.w;
      *(float4*)&Xs[r * 68 + cu] = xr;
    }
    __syncthreads();
  }

  // --- Ab f16 (row+trans, overwrites dead M); Kmat row 0 = Bb ---
  for (int idx = t; idx < 4096; idx += 512) {
    const int r = idx >> 6, cc = idx & 63;
    const _Float16 v = (_Float16)Xs[r * 68 + cc];
    PB0[mel(r, cc)] = v;
    PB1[mel(cc, r)] = v;
  }
  if (t < 64) {
    const float bb = Xs[t * 68 + 64];
    KC[t] = bb;
    PB2[mel(0, t)] = (_Float16)bb;
    PB3[mel(t, 0)] = (_Float16)bb;
  }
  __syncthreads();

  // --- Kmat row 1 = Ab@K0, one f32 matvec round (Xs still live) ---
  {
    const int mrow = t & 63;
    const float4* ar = (const float4*)(Xs + mrow * 68 + w * 8);
    const float4 av0 = ar[0], av1 = ar[1];
    const int jb = w * 8;
    RED[w][mrow] = av0.x * KC[jb] + av0.y * KC[jb + 1] + av0.z * KC[jb + 2] +
                   av0.w * KC[jb + 3] + av1.x * KC[jb + 4] + av1.y * KC[jb + 5] +
                   av1.z * KC[jb + 6] + av1.w * KC[jb + 7];
    __syncthreads();
    if (t < 64) {
      float s2 = 0.f;
#pragma unroll
      for (int qq = 0; qq < 8; ++qq) s2 += RED[qq][t];
      PB2[mel(1, t)] = (_Float16)s2;
      PB3[mel(t, 1)] = (_Float16)s2;
    }
    __syncthreads();
  }

  // --- power ladder + log-doubling Kmat (PB4/PB5 overwrite dead Xs) ---
  mmstep8(PB0, PB1, PB4, PB5, 0, 4, 64, w, c15, g); __syncthreads();  // Ab^2
  mmstep8(PB2, PB4, PB2, PB3, 2, 1, 2, w, c15, g);  __syncthreads();  // K[2,3]
  mmstep8(PB4, PB5, PB0, PB1, 0, 4, 64, w, c15, g); __syncthreads();  // Ab^4
  mmstep8(PB2, PB0, PB2, PB3, 4, 1, 4, w, c15, g);  __syncthreads();  // K[4..7]
  mmstep8(PB0, PB1, PB4, PB5, 0, 4, 64, w, c15, g); __syncthreads();  // Ab^8
  mmstep8(PB2, PB4, PB2, PB3, 8, 1, 8, w, c15, g);  __syncthreads();  // K[8..15]
  mmstep8(PB4, PB5, PB0, PB1, 0, 4, 64, w, c15, g); __syncthreads();  // Ab^16
  mmstep8(PB2, PB0, PB2, PB3, 16, 1, 16, w, c15, g); __syncthreads(); // K[16..31]
  mmstep8(PB0, PB1, PB4, PB5, 0, 4, 64, w, c15, g); __syncthreads();  // Ab^32
  mmstep8(PB2, PB4, PB2, PB3, 32, 2, 32, w, c15, g); __syncthreads(); // K[32..63]
  mmstep8(PB4, PB5, PB0, PB1, 0, 4, 64, w, c15, g); __syncthreads();  // G=Ab^64 ->PB0, G^T->PB1

  f16x8 bt[8][4];  // conv B-frags: [2*t + khalf][colblock]
  f16x8 bc[2][4];  // correction B-frags (G^4)^T
  auto LB = [&](f16x8* dst, const _Float16* BT, int kk) {
#pragma unroll
    for (int nb = 0; nb < 4; ++nb)
      dst[nb] = ldfrag(BT, (nb << 4) + c15, (kk << 2) + g);
  };

  LB(bt[0], PB3, 0); LB(bt[1], PB3, 1);                               // BK0 = Kmat
  mmstep8(PB2, PB0, PB4, PB5, 0, 4, 64, w, c15, g); __syncthreads();  // BK1 = Kmat@G^T
  LB(bt[2], PB5, 0); LB(bt[3], PB5, 1);
  mmstep8(PB4, PB0, PB2, PB3, 0, 4, 64, w, c15, g); __syncthreads();  // BK2
  LB(bt[4], PB3, 0); LB(bt[5], PB3, 1);
  mmstep8(PB2, PB0, PB4, PB5, 0, 4, 64, w, c15, g); __syncthreads();  // BK3
  LB(bt[6], PB5, 0); LB(bt[7], PB5, 1);
  mmstep8(PB1, PB0, PB2, PB3, 0, 4, 64, w, c15, g); __syncthreads();  // (G^2)^T, G^2
  mmstep8(PB2, PB3, PB4, PB1, 0, 4, 64, w, c15, g); __syncthreads();  // (G^4)^T; G^4->PB1
  LB(bc[0], PB1, 0); LB(bc[1], PB1, 1);
  __syncthreads();

  // --- main loop: 16 stages/chain, 2 waves/chain, barrier-free ---
  const int chain = w & 3;
  const int half = w >> 2;
  _Float16* ringw = RING + (chain << 12);
  float* outh = out + (h << 6);
  const int lanebase = (g << 3) - c15;

#pragma unroll 1
  for (int mstep = 0; mstep < 16; ++mstep) {
    const int c = chain + (mstep << 2);
    f32x4 acc[2][4];
#pragma unroll
    for (int ibl = 0; ibl < 2; ++ibl)
#pragma unroll
      for (int nb = 0; nb < 4; ++nb) acc[ibl][nb] = f32x4{0.f, 0.f, 0.f, 0.f};

    // conv over 4 lag-tiles (K-dim 256), Toeplitz A from shifted reversed-u
#pragma unroll
    for (int ks = 0; ks < 8; ++ks) {
      const int tt = ks >> 1;
      const int base = 4095 - 64 * (c - tt) + ((ks & 1) << 5) + lanebase;
#pragma unroll
      for (int ibl = 0; ibl < 2; ++ibl) {
        const int ib = (half << 1) + ibl;
        const int m0 = base - (ib << 4);
        const int lo = m0 & 3;
        const uint2* p = (const uint2*)(URV + lo * 4616 + (m0 - lo));
        union { f16x8 hv; uint2 u2[2]; } ua;
        ua.u2[0] = p[0];
        ua.u2[1] = p[1];
#pragma unroll
        for (int nb = 0; nb < 4; ++nb)
          acc[ibl][nb] = MF(ua.hv, bt[ks][nb], acc[ibl][nb]);
      }
    }
    // correction: X_{c-4} @ (G^4)^T  (ring rows are this wave's own)
    if (mstep > 0) {
#pragma unroll
      for (int kk = 0; kk < 2; ++kk)
#pragma unroll
        for (int ibl = 0; ibl < 2; ++ibl) {
          const int row = (((half << 1) + ibl) << 4) + c15;
          const f16x8 a = ldfrag(ringw, row, (kk << 2) + g);
#pragma unroll
          for (int nb = 0; nb < 4; ++nb)
            acc[ibl][nb] = MF(a, bc[kk][nb], acc[ibl][nb]);
        }
    }
    // write state ring (f16) + global out (f32), both wave-private
    const int ob = c << 6;
#pragma unroll
    for (int ibl = 0; ibl < 2; ++ibl)
#pragma unroll
      for (int nb = 0; nb < 4; ++nb) {
        const int n = (nb << 4) + c15;
#pragma unroll
        for (int j = 0; j < 4; ++j) {
          const int i = (((half << 1) + ibl) << 4) + (g << 2) + j;
          const float v = acc[ibl][nb][j];
          ringw[mel(i, n)] = (_Float16)v;
          outh[(size_t)(ob + i) * 16384 + n] = v;
        }
      }
  }
}

extern "C" void kernel_launch(void* const* d_in, const int* in_sizes, int n_in,
                              void* d_out, int out_size, void* d_ws,
                              size_t ws_size, hipStream_t stream) {
  const float* u = (const float*)d_in[0];
  const float* A = (const float*)d_in[1];
  const float* B = (const float*)d_in[2];
  const float* dt = (const float*)d_in[3];
  float* out = (float*)d_out;
  hippo_fused<<<dim3(NHEAD), dim3(512), 0, stream>>>(u, A, B, dt, out);
}